// Round 1
// baseline (936.170 us; speedup 1.0000x reference)
//
#include <hip/hip_runtime.h>

#define EPS 1e-5f

// ---------------- graph prep ----------------

__global__ __launch_bounds__(256) void hist_kernel(const int* __restrict__ ei, int E, int* __restrict__ count) {
    int e = blockIdx.x * blockDim.x + threadIdx.x;
    if (e < E) atomicAdd(&count[ei[E + e]], 1);   // col = target
}

__global__ __launch_bounds__(256) void dinv_kernel(const int* __restrict__ count, float* __restrict__ dinv, int n) {
    int i = blockIdx.x * blockDim.x + threadIdx.x;
    if (i < n) dinv[i] = rsqrtf((float)(count[i] + 1));   // +1 self-loop
}

__global__ __launch_bounds__(1024) void scan_kernel(const int* __restrict__ count, int* __restrict__ rowptr,
                                                    int* __restrict__ cursor, int n) {
    __shared__ int partial[1024];
    int tid = threadIdx.x;
    int chunk = (n + 1023) >> 10;
    int start = tid * chunk;
    int end = start + chunk; if (end > n) end = n; if (start > n) start = n;
    int s = 0;
    for (int i = start; i < end; ++i) s += count[i];
    partial[tid] = s;
    __syncthreads();
    // inclusive Hillis-Steele scan
    for (int off = 1; off < 1024; off <<= 1) {
        int v = (tid >= off) ? partial[tid - off] : 0;
        __syncthreads();
        partial[tid] += v;
        __syncthreads();
    }
    int base = (tid == 0) ? 0 : partial[tid - 1];
    for (int i = start; i < end; ++i) {
        rowptr[i] = base;
        cursor[i] = base;
        base += count[i];
    }
    if (tid == 1023) rowptr[n] = partial[1023];
}

__global__ __launch_bounds__(256) void scatter_kernel(const int* __restrict__ ei, int E,
                                                      int* __restrict__ cursor, int* __restrict__ csr) {
    int e = blockIdx.x * blockDim.x + threadIdx.x;
    if (e < E) {
        int r = ei[e];          // source
        int c = ei[E + e];      // target
        int pos = atomicAdd(&cursor[c], 1);
        csr[pos] = r;
    }
}

// ---------------- dense GEMM: [n,K] @ [K,64] -> [n,64] ----------------

template <int K>
__global__ __launch_bounds__(256) void gemm_kernel(const float* __restrict__ A, const float* __restrict__ W,
                                                   float* __restrict__ out, int n) {
    __shared__ float Wl[K * 64];
    __shared__ float Al[16 * K];
    int tid = threadIdx.x;
    for (int f = tid; f < K * 64; f += 256) Wl[f] = W[f];
    int row0 = blockIdx.x * 16;
    const float* Ab = A + (size_t)row0 * K;
    int limit = (n - row0) * K; if (limit > 16 * K) limit = 16 * K;
    for (int f = tid; f < 16 * K; f += 256) Al[f] = (f < limit) ? Ab[f] : 0.f;
    __syncthreads();

    int col = tid & 63, rq = tid >> 6;
    float acc0 = 0.f, acc1 = 0.f, acc2 = 0.f, acc3 = 0.f;
#pragma unroll 8
    for (int k = 0; k < K; ++k) {
        float wv = Wl[k * 64 + col];
        acc0 += Al[(rq * 4 + 0) * K + k] * wv;
        acc1 += Al[(rq * 4 + 1) * K + k] * wv;
        acc2 += Al[(rq * 4 + 2) * K + k] * wv;
        acc3 += Al[(rq * 4 + 3) * K + k] * wv;
    }
    int r = row0 + rq * 4;
    if (r + 0 < n) out[(size_t)(r + 0) * 64 + col] = acc0;
    if (r + 1 < n) out[(size_t)(r + 1) * 64 + col] = acc1;
    if (r + 2 < n) out[(size_t)(r + 2) * 64 + col] = acc2;
    if (r + 3 < n) out[(size_t)(r + 3) * 64 + col] = acc3;
}

// ---------------- aggregation + bias + BN(eval) + ReLU (+classifier) ----------------

template <bool FUSE_CLS>
__global__ __launch_bounds__(256) void agg_kernel(const float* __restrict__ t, const float* __restrict__ dinv,
                                                  const int* __restrict__ rowptr, const int* __restrict__ csr,
                                                  const float* __restrict__ bias, const float* __restrict__ gamma,
                                                  const float* __restrict__ beta, const float* __restrict__ mean,
                                                  const float* __restrict__ var, float* __restrict__ out,
                                                  const float* __restrict__ cls_w, const float* __restrict__ cls_b,
                                                  int n) {
    int wave = threadIdx.x >> 6;
    int lane = threadIdx.x & 63;
    int i = blockIdx.x * (blockDim.x >> 6) + wave;
    if (i >= n) return;

    float di = dinv[i];
    float acc = di * di * t[(size_t)i * 64 + lane];   // self-loop
    int e0 = rowptr[i], e1 = rowptr[i + 1];
    for (int e = e0; e < e1; ++e) {
        int r = csr[e];
        acc += di * dinv[r] * t[(size_t)r * 64 + lane];
    }
    acc += bias[lane];
    float sc = gamma[lane] * rsqrtf(var[lane] + EPS);
    acc = (acc - mean[lane]) * sc + beta[lane];
    acc = fmaxf(acc, 0.f);

    if (!FUSE_CLS) {
        out[(size_t)i * 64 + lane] = acc;
    } else {
        float c0 = acc * cls_w[lane * 2 + 0];
        float c1 = acc * cls_w[lane * 2 + 1];
        for (int off = 32; off > 0; off >>= 1) {
            c0 += __shfl_down(c0, off);
            c1 += __shfl_down(c1, off);
        }
        if (lane == 0) {
            out[(size_t)i * 2 + 0] = c0 + cls_b[0];
            out[(size_t)i * 2 + 1] = c1 + cls_b[1];
        }
    }
}

// ---------------- launch ----------------

extern "C" void kernel_launch(void* const* d_in, const int* in_sizes, int n_in,
                              void* d_out, int out_size, void* d_ws, size_t ws_size,
                              hipStream_t stream) {
    const float* x      = (const float*)d_in[0];
    const int*   ei     = (const int*)d_in[1];
    const float* w0     = (const float*)d_in[2];
    const float* w1     = (const float*)d_in[3];
    const float* w2     = (const float*)d_in[4];
    const float* biases = (const float*)d_in[5];
    const float* gamma  = (const float*)d_in[6];
    const float* beta   = (const float*)d_in[7];
    const float* rmean  = (const float*)d_in[8];
    const float* rvar   = (const float*)d_in[9];
    const float* cls_w  = (const float*)d_in[10];
    const float* cls_b  = (const float*)d_in[11];
    float* out = (float*)d_out;

    const int IN = 128, H = 64;
    const int N = in_sizes[0] / IN;   // 100000
    const int E = in_sizes[1] / 2;    // 1200000

    char* p = (char*)d_ws;
    auto carve = [&](size_t bytes) { void* q = (void*)p; p += (bytes + 255) & ~(size_t)255; return q; };
    float* dinv   = (float*)carve((size_t)N * 4);
    int*   count  = (int*)carve((size_t)N * 4);
    int*   rowptr = (int*)carve((size_t)(N + 1) * 4);
    int*   cursor = (int*)carve((size_t)N * 4);
    int*   csr    = (int*)carve((size_t)E * 4);
    float* tbuf   = (float*)carve((size_t)N * H * 4);
    float* hbuf   = (float*)carve((size_t)N * H * 4);

    hipMemsetAsync(count, 0, (size_t)N * 4, stream);
    hist_kernel<<<(E + 255) / 256, 256, 0, stream>>>(ei, E, count);
    dinv_kernel<<<(N + 255) / 256, 256, 0, stream>>>(count, dinv, N);
    scan_kernel<<<1, 1024, 0, stream>>>(count, rowptr, cursor, N);
    scatter_kernel<<<(E + 255) / 256, 256, 0, stream>>>(ei, E, cursor, csr);

    int gemm_grid = (N + 15) / 16;
    int agg_grid  = (N + 3) / 4;

    // layer 0
    gemm_kernel<128><<<gemm_grid, 256, 0, stream>>>(x, w0, tbuf, N);
    agg_kernel<false><<<agg_grid, 256, 0, stream>>>(tbuf, dinv, rowptr, csr,
        biases + 0, gamma + 0, beta + 0, rmean + 0, rvar + 0, hbuf, nullptr, nullptr, N);
    // layer 1
    gemm_kernel<64><<<gemm_grid, 256, 0, stream>>>(hbuf, w1, tbuf, N);
    agg_kernel<false><<<agg_grid, 256, 0, stream>>>(tbuf, dinv, rowptr, csr,
        biases + H, gamma + H, beta + H, rmean + H, rvar + H, hbuf, nullptr, nullptr, N);
    // layer 2 + classifier
    gemm_kernel<64><<<gemm_grid, 256, 0, stream>>>(hbuf, w2, tbuf, N);
    agg_kernel<true><<<agg_grid, 256, 0, stream>>>(tbuf, dinv, rowptr, csr,
        biases + 2 * H, gamma + 2 * H, beta + 2 * H, rmean + 2 * H, rvar + 2 * H, out, cls_w, cls_b, N);
}

// Round 2
// 712.737 us; speedup vs baseline: 1.3135x; 1.3135x over previous
//
#include <hip/hip_runtime.h>

#define EPS 1e-5f
#define SCAN_CHUNK 1024   // elements per block in the parallel scan

// ---------------- graph prep ----------------

__global__ __launch_bounds__(256) void hist_kernel(const int* __restrict__ ei, int E, int* __restrict__ count) {
    int e = blockIdx.x * blockDim.x + threadIdx.x;
    if (e < E) atomicAdd(&count[ei[E + e]], 1);   // col = target
}

__global__ __launch_bounds__(256) void dinv_kernel(const int* __restrict__ count, float* __restrict__ dinv, int n) {
    int i = blockIdx.x * blockDim.x + threadIdx.x;
    if (i < n) dinv[i] = rsqrtf((float)(count[i] + 1));   // +1 self-loop
}

// pass 1: per-block (1024 elems) local exclusive scan into rowptr, block total into bsum
__global__ __launch_bounds__(256) void scan_pass1(const int* __restrict__ count, int* __restrict__ rowptr,
                                                  int* __restrict__ bsum, int n) {
    __shared__ int ssum[256];
    int t = threadIdx.x;
    int base = blockIdx.x * SCAN_CHUNK + t * 4;
    int v0 = 0, v1 = 0, v2 = 0, v3 = 0;
    if (base + 3 < n) {
        int4 vv = *(const int4*)(count + base);
        v0 = vv.x; v1 = vv.y; v2 = vv.z; v3 = vv.w;
    } else {
        if (base + 0 < n) v0 = count[base + 0];
        if (base + 1 < n) v1 = count[base + 1];
        if (base + 2 < n) v2 = count[base + 2];
        if (base + 3 < n) v3 = count[base + 3];
    }
    int s = v0 + v1 + v2 + v3;
    ssum[t] = s;
    __syncthreads();
    for (int off = 1; off < 256; off <<= 1) {
        int u = (t >= off) ? ssum[t - off] : 0;
        __syncthreads();
        ssum[t] += u;
        __syncthreads();
    }
    int excl = ssum[t] - s;
    int p0 = excl, p1 = excl + v0, p2 = excl + v0 + v1, p3 = excl + v0 + v1 + v2;
    if (base + 3 < n) {
        *(int4*)(rowptr + base) = make_int4(p0, p1, p2, p3);
    } else {
        if (base + 0 < n) rowptr[base + 0] = p0;
        if (base + 1 < n) rowptr[base + 1] = p1;
        if (base + 2 < n) rowptr[base + 2] = p2;
        if (base + 3 < n) rowptr[base + 3] = p3;
    }
    if (t == 255) bsum[blockIdx.x] = ssum[255];
}

// pass 2: scan block sums (nb <= 1024), write exclusive block offsets + rowptr[n]
__global__ __launch_bounds__(1024) void scan_pass2(const int* __restrict__ bsum, int* __restrict__ boffs,
                                                   int* __restrict__ rowptr, int nb, int n) {
    __shared__ int s[1024];
    int t = threadIdx.x;
    int v = (t < nb) ? bsum[t] : 0;
    s[t] = v;
    __syncthreads();
    for (int off = 1; off < 1024; off <<= 1) {
        int u = (t >= off) ? s[t - off] : 0;
        __syncthreads();
        s[t] += u;
        __syncthreads();
    }
    if (t < nb) boffs[t] = s[t] - v;
    if (t == 1023) rowptr[n] = s[1023];
}

// pass 3: add block offsets, materialize cursor
__global__ __launch_bounds__(256) void scan_pass3(int* __restrict__ rowptr, int* __restrict__ cursor,
                                                  const int* __restrict__ boffs, int n) {
    int t = threadIdx.x;
    int base = blockIdx.x * SCAN_CHUNK + t * 4;
    int off = boffs[blockIdx.x];
    if (base + 3 < n) {
        int4 v = *(int4*)(rowptr + base);
        v.x += off; v.y += off; v.z += off; v.w += off;
        *(int4*)(rowptr + base) = v;
        *(int4*)(cursor + base) = v;
    } else {
        for (int j = 0; j < 4; ++j)
            if (base + j < n) { int v = rowptr[base + j] + off; rowptr[base + j] = v; cursor[base + j] = v; }
    }
}

__global__ __launch_bounds__(256) void scatter_kernel(const int* __restrict__ ei, int E,
                                                      int* __restrict__ cursor, int* __restrict__ csr) {
    int e = blockIdx.x * blockDim.x + threadIdx.x;
    if (e < E) {
        int r = ei[e];          // source
        int c = ei[E + e];      // target
        int pos = atomicAdd(&cursor[c], 1);
        csr[pos] = r;
    }
}

// ---------------- dense GEMM: [n,K] @ [K,64] -> [n,64] ----------------

template <int K>
__global__ __launch_bounds__(256) void gemm_kernel(const float* __restrict__ A, const float* __restrict__ W,
                                                   float* __restrict__ out, int n) {
    __shared__ float Wl[K * 64];
    __shared__ float Al[16 * K];
    int tid = threadIdx.x;
    for (int f = tid; f < K * 64; f += 256) Wl[f] = W[f];
    int row0 = blockIdx.x * 16;
    const float* Ab = A + (size_t)row0 * K;
    int limit = (n - row0) * K; if (limit > 16 * K) limit = 16 * K;
    for (int f = tid; f < 16 * K; f += 256) Al[f] = (f < limit) ? Ab[f] : 0.f;
    __syncthreads();

    int col = tid & 63, rq = tid >> 6;
    float acc0 = 0.f, acc1 = 0.f, acc2 = 0.f, acc3 = 0.f;
#pragma unroll 8
    for (int k = 0; k < K; ++k) {
        float wv = Wl[k * 64 + col];
        acc0 += Al[(rq * 4 + 0) * K + k] * wv;
        acc1 += Al[(rq * 4 + 1) * K + k] * wv;
        acc2 += Al[(rq * 4 + 2) * K + k] * wv;
        acc3 += Al[(rq * 4 + 3) * K + k] * wv;
    }
    int r = row0 + rq * 4;
    if (r + 0 < n) out[(size_t)(r + 0) * 64 + col] = acc0;
    if (r + 1 < n) out[(size_t)(r + 1) * 64 + col] = acc1;
    if (r + 2 < n) out[(size_t)(r + 2) * 64 + col] = acc2;
    if (r + 3 < n) out[(size_t)(r + 3) * 64 + col] = acc3;
}

// ---------------- aggregation + bias + BN(eval) + ReLU (+classifier) ----------------

template <bool FUSE_CLS>
__global__ __launch_bounds__(256) void agg_kernel(const float* __restrict__ t, const float* __restrict__ dinv,
                                                  const int* __restrict__ rowptr, const int* __restrict__ csr,
                                                  const float* __restrict__ bias, const float* __restrict__ gamma,
                                                  const float* __restrict__ beta, const float* __restrict__ mean,
                                                  const float* __restrict__ var, float* __restrict__ out,
                                                  const float* __restrict__ cls_w, const float* __restrict__ cls_b,
                                                  int n) {
    int wave = threadIdx.x >> 6;
    int lane = threadIdx.x & 63;
    int i = blockIdx.x * (blockDim.x >> 6) + wave;
    if (i >= n) return;

    float di = dinv[i];
    float acc = di * di * t[(size_t)i * 64 + lane];   // self-loop
    int e0 = rowptr[i], e1 = rowptr[i + 1];
    for (int e = e0; e < e1; ++e) {
        int r = csr[e];
        acc += di * dinv[r] * t[(size_t)r * 64 + lane];
    }
    acc += bias[lane];
    float sc = gamma[lane] * rsqrtf(var[lane] + EPS);
    acc = (acc - mean[lane]) * sc + beta[lane];
    acc = fmaxf(acc, 0.f);

    if (!FUSE_CLS) {
        out[(size_t)i * 64 + lane] = acc;
    } else {
        float c0 = acc * cls_w[lane * 2 + 0];
        float c1 = acc * cls_w[lane * 2 + 1];
        for (int off = 32; off > 0; off >>= 1) {
            c0 += __shfl_down(c0, off);
            c1 += __shfl_down(c1, off);
        }
        if (lane == 0) {
            out[(size_t)i * 2 + 0] = c0 + cls_b[0];
            out[(size_t)i * 2 + 1] = c1 + cls_b[1];
        }
    }
}

// ---------------- launch ----------------

extern "C" void kernel_launch(void* const* d_in, const int* in_sizes, int n_in,
                              void* d_out, int out_size, void* d_ws, size_t ws_size,
                              hipStream_t stream) {
    const float* x      = (const float*)d_in[0];
    const int*   ei     = (const int*)d_in[1];
    const float* w0     = (const float*)d_in[2];
    const float* w1     = (const float*)d_in[3];
    const float* w2     = (const float*)d_in[4];
    const float* biases = (const float*)d_in[5];
    const float* gamma  = (const float*)d_in[6];
    const float* beta   = (const float*)d_in[7];
    const float* rmean  = (const float*)d_in[8];
    const float* rvar   = (const float*)d_in[9];
    const float* cls_w  = (const float*)d_in[10];
    const float* cls_b  = (const float*)d_in[11];
    float* out = (float*)d_out;

    const int IN = 128, H = 64;
    const int N = in_sizes[0] / IN;   // 100000
    const int E = in_sizes[1] / 2;    // 1200000

    char* p = (char*)d_ws;
    auto carve = [&](size_t bytes) { void* q = (void*)p; p += (bytes + 255) & ~(size_t)255; return q; };
    float* dinv   = (float*)carve((size_t)N * 4);
    int*   count  = (int*)carve((size_t)N * 4);
    int*   rowptr = (int*)carve((size_t)(N + 1) * 4);
    int*   cursor = (int*)carve((size_t)N * 4);
    int*   csr    = (int*)carve((size_t)E * 4);
    int*   bsum   = (int*)carve((size_t)1024 * 4);
    int*   boffs  = (int*)carve((size_t)1024 * 4);
    float* tbuf   = (float*)carve((size_t)N * H * 4);
    float* hbuf   = (float*)carve((size_t)N * H * 4);

    int nb = (N + SCAN_CHUNK - 1) / SCAN_CHUNK;   // 98 for N=100000

    hipMemsetAsync(count, 0, (size_t)N * 4, stream);
    hist_kernel<<<(E + 255) / 256, 256, 0, stream>>>(ei, E, count);
    dinv_kernel<<<(N + 255) / 256, 256, 0, stream>>>(count, dinv, N);
    scan_pass1<<<nb, 256, 0, stream>>>(count, rowptr, bsum, N);
    scan_pass2<<<1, 1024, 0, stream>>>(bsum, boffs, rowptr, nb, N);
    scan_pass3<<<nb, 256, 0, stream>>>(rowptr, cursor, boffs, N);
    scatter_kernel<<<(E + 255) / 256, 256, 0, stream>>>(ei, E, cursor, csr);

    int gemm_grid = (N + 15) / 16;
    int agg_grid  = (N + 3) / 4;

    // layer 0
    gemm_kernel<128><<<gemm_grid, 256, 0, stream>>>(x, w0, tbuf, N);
    agg_kernel<false><<<agg_grid, 256, 0, stream>>>(tbuf, dinv, rowptr, csr,
        biases + 0, gamma + 0, beta + 0, rmean + 0, rvar + 0, hbuf, nullptr, nullptr, N);
    // layer 1
    gemm_kernel<64><<<gemm_grid, 256, 0, stream>>>(hbuf, w1, tbuf, N);
    agg_kernel<false><<<agg_grid, 256, 0, stream>>>(tbuf, dinv, rowptr, csr,
        biases + H, gamma + H, beta + H, rmean + H, rvar + H, hbuf, nullptr, nullptr, N);
    // layer 2 + classifier
    gemm_kernel<64><<<gemm_grid, 256, 0, stream>>>(hbuf, w2, tbuf, N);
    agg_kernel<true><<<agg_grid, 256, 0, stream>>>(tbuf, dinv, rowptr, csr,
        biases + 2 * H, gamma + 2 * H, beta + 2 * H, rmean + 2 * H, rvar + 2 * H, out, cls_w, cls_b, N);
}

// Round 3
// 508.537 us; speedup vs baseline: 1.8409x; 1.4015x over previous
//
#include <hip/hip_runtime.h>
#include <hip/hip_fp16.h>

#define EPS 1e-5f
#define SCAN_CHUNK 1024   // elements per block in the parallel scan

// ---------------- graph prep ----------------

__global__ __launch_bounds__(256) void hist_kernel(const int* __restrict__ ei, int E, int* __restrict__ count) {
    int e = blockIdx.x * blockDim.x + threadIdx.x;
    if (e < E) atomicAdd(&count[ei[E + e]], 1);   // col = target
}

__global__ __launch_bounds__(256) void dinv_kernel(const int* __restrict__ count, float* __restrict__ dinv, int n) {
    int i = blockIdx.x * blockDim.x + threadIdx.x;
    if (i < n) dinv[i] = rsqrtf((float)(count[i] + 1));   // +1 self-loop
}

// pass 1: per-block (1024 elems) local exclusive scan into rowptr, block total into bsum
__global__ __launch_bounds__(256) void scan_pass1(const int* __restrict__ count, int* __restrict__ rowptr,
                                                  int* __restrict__ bsum, int n) {
    __shared__ int ssum[256];
    int t = threadIdx.x;
    int base = blockIdx.x * SCAN_CHUNK + t * 4;
    int v0 = 0, v1 = 0, v2 = 0, v3 = 0;
    if (base + 3 < n) {
        int4 vv = *(const int4*)(count + base);
        v0 = vv.x; v1 = vv.y; v2 = vv.z; v3 = vv.w;
    } else {
        if (base + 0 < n) v0 = count[base + 0];
        if (base + 1 < n) v1 = count[base + 1];
        if (base + 2 < n) v2 = count[base + 2];
        if (base + 3 < n) v3 = count[base + 3];
    }
    int s = v0 + v1 + v2 + v3;
    ssum[t] = s;
    __syncthreads();
    for (int off = 1; off < 256; off <<= 1) {
        int u = (t >= off) ? ssum[t - off] : 0;
        __syncthreads();
        ssum[t] += u;
        __syncthreads();
    }
    int excl = ssum[t] - s;
    int p0 = excl, p1 = excl + v0, p2 = excl + v0 + v1, p3 = excl + v0 + v1 + v2;
    if (base + 3 < n) {
        *(int4*)(rowptr + base) = make_int4(p0, p1, p2, p3);
    } else {
        if (base + 0 < n) rowptr[base + 0] = p0;
        if (base + 1 < n) rowptr[base + 1] = p1;
        if (base + 2 < n) rowptr[base + 2] = p2;
        if (base + 3 < n) rowptr[base + 3] = p3;
    }
    if (t == 255) bsum[blockIdx.x] = ssum[255];
}

// pass 2: scan block sums (nb <= 1024), write exclusive block offsets + rowptr[n]
__global__ __launch_bounds__(1024) void scan_pass2(const int* __restrict__ bsum, int* __restrict__ boffs,
                                                   int* __restrict__ rowptr, int nb, int n) {
    __shared__ int s[1024];
    int t = threadIdx.x;
    int v = (t < nb) ? bsum[t] : 0;
    s[t] = v;
    __syncthreads();
    for (int off = 1; off < 1024; off <<= 1) {
        int u = (t >= off) ? s[t - off] : 0;
        __syncthreads();
        s[t] += u;
        __syncthreads();
    }
    if (t < nb) boffs[t] = s[t] - v;
    if (t == 1023) rowptr[n] = s[1023];
}

// pass 3: add block offsets, materialize cursor
__global__ __launch_bounds__(256) void scan_pass3(int* __restrict__ rowptr, int* __restrict__ cursor,
                                                  const int* __restrict__ boffs, int n) {
    int t = threadIdx.x;
    int base = blockIdx.x * SCAN_CHUNK + t * 4;
    int off = boffs[blockIdx.x];
    if (base + 3 < n) {
        int4 v = *(int4*)(rowptr + base);
        v.x += off; v.y += off; v.z += off; v.w += off;
        *(int4*)(rowptr + base) = v;
        *(int4*)(cursor + base) = v;
    } else {
        for (int j = 0; j < 4; ++j)
            if (base + j < n) { int v = rowptr[base + j] + off; rowptr[base + j] = v; cursor[base + j] = v; }
    }
}

// scatter: CSR entry = (source index, norm weight dinv[src]*dinv[dst]) packed as int2
__global__ __launch_bounds__(256) void scatter_kernel(const int* __restrict__ ei, int E,
                                                      const float* __restrict__ dinv,
                                                      int* __restrict__ cursor, int2* __restrict__ csrw) {
    int e = blockIdx.x * blockDim.x + threadIdx.x;
    if (e < E) {
        int r = ei[e];          // source
        int c = ei[E + e];      // target
        int pos = atomicAdd(&cursor[c], 1);
        float w = dinv[r] * dinv[c];
        csrw[pos] = make_int2(r, __float_as_int(w));
    }
}

// ---------------- dense GEMM: [n,K](f32) @ [K,64](f32) -> [n,64] (f16) ----------------

template <int K>
__global__ __launch_bounds__(256) void gemm_kernel(const float* __restrict__ A, const float* __restrict__ W,
                                                   __half* __restrict__ out, int n) {
    __shared__ float Wl[K * 64];
    __shared__ float Al[16 * K];
    int tid = threadIdx.x;
    for (int f = tid; f < K * 64; f += 256) Wl[f] = W[f];
    int row0 = blockIdx.x * 16;
    const float* Ab = A + (size_t)row0 * K;
    int limit = (n - row0) * K; if (limit > 16 * K) limit = 16 * K;
    for (int f = tid; f < 16 * K; f += 256) Al[f] = (f < limit) ? Ab[f] : 0.f;
    __syncthreads();

    int col = tid & 63, rq = tid >> 6;
    float acc0 = 0.f, acc1 = 0.f, acc2 = 0.f, acc3 = 0.f;
#pragma unroll 8
    for (int k = 0; k < K; ++k) {
        float wv = Wl[k * 64 + col];
        acc0 += Al[(rq * 4 + 0) * K + k] * wv;
        acc1 += Al[(rq * 4 + 1) * K + k] * wv;
        acc2 += Al[(rq * 4 + 2) * K + k] * wv;
        acc3 += Al[(rq * 4 + 3) * K + k] * wv;
    }
    int r = row0 + rq * 4;
    if (r + 0 < n) out[(size_t)(r + 0) * 64 + col] = __float2half(acc0);
    if (r + 1 < n) out[(size_t)(r + 1) * 64 + col] = __float2half(acc1);
    if (r + 2 < n) out[(size_t)(r + 2) * 64 + col] = __float2half(acc2);
    if (r + 3 < n) out[(size_t)(r + 3) * 64 + col] = __float2half(acc3);
}

// ---------------- aggregation + bias + BN(eval) + ReLU (+classifier) ----------------

template <bool FUSE_CLS>
__global__ __launch_bounds__(256) void agg_kernel(const __half* __restrict__ t, const float* __restrict__ dinv,
                                                  const int* __restrict__ rowptr, const int2* __restrict__ csrw,
                                                  const float* __restrict__ bias, const float* __restrict__ gamma,
                                                  const float* __restrict__ beta, const float* __restrict__ mean,
                                                  const float* __restrict__ var, float* __restrict__ out,
                                                  const float* __restrict__ cls_w, const float* __restrict__ cls_b,
                                                  int n) {
    int wave = threadIdx.x >> 6;
    int lane = threadIdx.x & 63;
    int i = blockIdx.x * (blockDim.x >> 6) + wave;
    if (i >= n) return;

    float di = dinv[i];
    float acc = di * di * __half2float(t[(size_t)i * 64 + lane]);   // self-loop
    int e0 = rowptr[i], e1 = rowptr[i + 1];
    int e = e0;
    // unrolled x4: 4 independent row gathers in flight
    for (; e + 3 < e1; e += 4) {
        int2 a0 = csrw[e + 0], a1 = csrw[e + 1], a2 = csrw[e + 2], a3 = csrw[e + 3];
        float v0 = __half2float(t[(size_t)a0.x * 64 + lane]);
        float v1 = __half2float(t[(size_t)a1.x * 64 + lane]);
        float v2 = __half2float(t[(size_t)a2.x * 64 + lane]);
        float v3 = __half2float(t[(size_t)a3.x * 64 + lane]);
        acc += __int_as_float(a0.y) * v0;
        acc += __int_as_float(a1.y) * v1;
        acc += __int_as_float(a2.y) * v2;
        acc += __int_as_float(a3.y) * v3;
    }
    for (; e < e1; ++e) {
        int2 a = csrw[e];
        acc += __int_as_float(a.y) * __half2float(t[(size_t)a.x * 64 + lane]);
    }

    acc += bias[lane];
    float sc = gamma[lane] * rsqrtf(var[lane] + EPS);
    acc = (acc - mean[lane]) * sc + beta[lane];
    acc = fmaxf(acc, 0.f);

    if (!FUSE_CLS) {
        out[(size_t)i * 64 + lane] = acc;
    } else {
        float c0 = acc * cls_w[lane * 2 + 0];
        float c1 = acc * cls_w[lane * 2 + 1];
        for (int off = 32; off > 0; off >>= 1) {
            c0 += __shfl_down(c0, off);
            c1 += __shfl_down(c1, off);
        }
        if (lane == 0) {
            out[(size_t)i * 2 + 0] = c0 + cls_b[0];
            out[(size_t)i * 2 + 1] = c1 + cls_b[1];
        }
    }
}

// ---------------- launch ----------------

extern "C" void kernel_launch(void* const* d_in, const int* in_sizes, int n_in,
                              void* d_out, int out_size, void* d_ws, size_t ws_size,
                              hipStream_t stream) {
    const float* x      = (const float*)d_in[0];
    const int*   ei     = (const int*)d_in[1];
    const float* w0     = (const float*)d_in[2];
    const float* w1     = (const float*)d_in[3];
    const float* w2     = (const float*)d_in[4];
    const float* biases = (const float*)d_in[5];
    const float* gamma  = (const float*)d_in[6];
    const float* beta   = (const float*)d_in[7];
    const float* rmean  = (const float*)d_in[8];
    const float* rvar   = (const float*)d_in[9];
    const float* cls_w  = (const float*)d_in[10];
    const float* cls_b  = (const float*)d_in[11];
    float* out = (float*)d_out;

    const int IN = 128, H = 64;
    const int N = in_sizes[0] / IN;   // 100000
    const int E = in_sizes[1] / 2;    // 1200000

    char* p = (char*)d_ws;
    auto carve = [&](size_t bytes) { void* q = (void*)p; p += (bytes + 255) & ~(size_t)255; return q; };
    float* dinv   = (float*)carve((size_t)N * 4);
    int*   count  = (int*)carve((size_t)N * 4);
    int*   rowptr = (int*)carve((size_t)(N + 1) * 4);
    int*   cursor = (int*)carve((size_t)N * 4);
    int2*  csrw   = (int2*)carve((size_t)E * 8);
    int*   bsum   = (int*)carve((size_t)1024 * 4);
    int*   boffs  = (int*)carve((size_t)1024 * 4);
    __half* tbuf  = (__half*)carve((size_t)N * H * 2);
    float* hbuf   = (float*)carve((size_t)N * H * 4);

    int nb = (N + SCAN_CHUNK - 1) / SCAN_CHUNK;   // 98 for N=100000

    hipMemsetAsync(count, 0, (size_t)N * 4, stream);
    hist_kernel<<<(E + 255) / 256, 256, 0, stream>>>(ei, E, count);
    dinv_kernel<<<(N + 255) / 256, 256, 0, stream>>>(count, dinv, N);
    scan_pass1<<<nb, 256, 0, stream>>>(count, rowptr, bsum, N);
    scan_pass2<<<1, 1024, 0, stream>>>(bsum, boffs, rowptr, nb, N);
    scan_pass3<<<nb, 256, 0, stream>>>(rowptr, cursor, boffs, N);
    scatter_kernel<<<(E + 255) / 256, 256, 0, stream>>>(ei, E, dinv, cursor, csrw);

    int gemm_grid = (N + 15) / 16;
    int agg_grid  = (N + 3) / 4;

    // layer 0
    gemm_kernel<128><<<gemm_grid, 256, 0, stream>>>(x, w0, tbuf, N);
    agg_kernel<false><<<agg_grid, 256, 0, stream>>>(tbuf, dinv, rowptr, csrw,
        biases + 0, gamma + 0, beta + 0, rmean + 0, rvar + 0, hbuf, nullptr, nullptr, N);
    // layer 1
    gemm_kernel<64><<<gemm_grid, 256, 0, stream>>>(hbuf, w1, tbuf, N);
    agg_kernel<false><<<agg_grid, 256, 0, stream>>>(tbuf, dinv, rowptr, csrw,
        biases + H, gamma + H, beta + H, rmean + H, rvar + H, hbuf, nullptr, nullptr, N);
    // layer 2 + classifier
    gemm_kernel<64><<<gemm_grid, 256, 0, stream>>>(hbuf, w2, tbuf, N);
    agg_kernel<true><<<agg_grid, 256, 0, stream>>>(tbuf, dinv, rowptr, csrw,
        biases + 2 * H, gamma + 2 * H, beta + 2 * H, rmean + 2 * H, rvar + 2 * H, out, cls_w, cls_b, N);
}